// Round 4
// baseline (141.366 us; speedup 1.0000x reference)
//
#include <hip/hip_runtime.h>

typedef float v2f __attribute__((ext_vector_type(2)));

// ---- problem ----
// x:[4,16,8,64,64] f32, w_q/w_k/w_v:[64,8] f32, w_p:[2] f32
// out:[4,16,64,64,64] f32
// Attention batch B = bb*64 + o: q-side channel i (all 16) row o;
// k/v-side channel o>>2, w_k/w_v rows (o&3)*16+j; uk += 2*pe; scale 0.125
// folded into w_q (plus log2e when exp2 available); residual = mean over m;
// single-pass softmax (|logit| << 88): out = (sum_j e_j*uv_j)/(sum_j e_j).
//
// R14: single-barrier restructure. R10/R13 both sat at ~53 us with very
// different LDS/VALU mixes -> latency/serialization-bound, not throughput.
// The s_xk LDS round-trip existed only to broadcast 4 KB of cache-resident
// x to the 16 j-threads; the L1 does that broadcast for free (same-address
// lanes coalesce to one line). So stage-2 threads now load their x straight
// from global and the first barrier + s_xk staging disappear entirely:
//   per-wave chain: [kv loads -> uk/uv fma -> ds_write | q loads -> q conv]
//                   -> ONE barrier -> attention.
// LDS 20480 -> 16384 B; LDS ops/thread ~69 -> ~37; math bit-identical.

#if __has_builtin(__builtin_amdgcn_exp2f)
  #define EXP_FN(x) __builtin_amdgcn_exp2f(x)
  #define QSCALE 0.18033688011112043f   // 0.125 * log2(e)
#else
  #define EXP_FN(x) __expf(x)
  #define QSCALE 0.125f
#endif
#if __has_builtin(__builtin_amdgcn_rcpf)
  #define RCP_FN(x) __builtin_amdgcn_rcpf(x)
#else
  #define RCP_FN(x) (1.0f/(x))
#endif

__global__ __launch_bounds__(256, 4) void adapt_attn(
    const float* __restrict__ x,  const float* __restrict__ wq,
    const float* __restrict__ wk, const float* __restrict__ wv,
    const float* __restrict__ wp, float* __restrict__ out)
{
    __shared__ float4 s_uk[2][16][16];   // 8 KB [t][j][p]: (y0x0,y0x1,y1x0,y1x1)
    __shared__ float4 s_uv[2][16][16];   // 8 KB  -> 16384 B total

    const int tid = threadIdx.x;          // 0..255
    const int bid = blockIdx.x;           // ((bb*64+o)*32)+tg ; 8192 blocks
    const int tg = bid & 31;
    const int o  = (bid >> 5) & 63;
    const int bb = bid >> 11;
    const int r = o & 3, qch = o >> 2;

    const v2f* __restrict__ x2 = (const v2f*)x;  // v2f strides: m 2048, row 32

    // Both tiles of this block share the row pair y0,y0+1 and split the
    // 64-wide row into two 32-float halves (t=0: cols 0..31, t=1: 32..63).
    const int y0 = tg << 1;

    // ---- phase 1: k/v conv straight from global (x is L1/L2-resident;
    //      the 16 j-threads per pixel read identical addresses -> the wave
    //      coalescer collapses them to one 128B line) ----
    const int p2 = tid & 15, j2 = (tid >> 4) & 15;

    float wkj[8], wvj[8];
    {
        const float4* wk4 = (const float4*)wk;
        const float4* wv4 = (const float4*)wv;
        const int rb = (r * 16 + j2) * 2;
        *(float4*)&wkj[0] = wk4[rb];   *(float4*)&wkj[4] = wk4[rb + 1];
        *(float4*)&wvj[0] = wv4[rb];   *(float4*)&wvj[4] = wv4[rb + 1];
    }
    const float wp0 = wp[0], wp1 = wp[1];
    const float step = 2.0f / 63.0f;
    const float ly0 = -1.0f + step * (float)y0;
    const float ly1 = ly0 + step;

    const int baseKV = (bb * 16 + qch) * 16384 + y0 * 32 + p2;
    #pragma unroll
    for (int t = 0; t < 2; t++) {
        const int wwp = (t << 4) + p2;            // v2f column
        const float lx0 = -1.0f + step * (float)(wwp << 1);
        const float lx1 = lx0 + step;
        v2f ka = { 2.0f * (wp0 * lx0 + wp1 * ly0), 2.0f * (wp0 * lx1 + wp1 * ly0) };
        v2f kb = { 2.0f * (wp0 * lx0 + wp1 * ly1), 2.0f * (wp0 * lx1 + wp1 * ly1) };
        v2f va = {0.f, 0.f}, vb = {0.f, 0.f};

        const int bkt = baseKV + (t << 4);
        #pragma unroll
        for (int m = 0; m < 8; m++) {
            const v2f xa = x2[bkt + m * 2048];        // row y0
            const v2f xb = x2[bkt + m * 2048 + 32];   // row y0+1
            ka += xa * wkj[m]; kb += xb * wkj[m];
            va += xa * wvj[m]; vb += xb * wvj[m];
        }
        s_uk[t][j2][p2] = make_float4(ka.x, ka.y, kb.x, kb.y);
        s_uv[t][j2][p2] = make_float4(va.x, va.y, vb.x, vb.y);
    }

    // ---- phase 2: q loads + q-conv + residual (independent of phase 1) ----
    const int p3 = tid & 15, ig = (tid >> 4) & 7, t3 = tid >> 7;
    const int sp = y0 * 32 + (t3 << 4) + p3;      // v2f offset in 64x64 plane

    float wqr[8];
    #pragma unroll
    for (int m = 0; m < 8; m++)
        wqr[m] = QSCALE * wq[(o << 3) + m];       // uniform scalar loads

    v2f qa0[8], qb0[8], qa1[8], qb1[8];
    {
        const int bq0 = (bb * 16 + ig * 2) * 16384 + sp;
        const int bq1 = bq0 + 16384;
        #pragma unroll
        for (int m = 0; m < 8; m++) {             // lanes 0-15 coalesced 128B
            qa0[m] = x2[bq0 + m * 2048];
            qb0[m] = x2[bq0 + m * 2048 + 32];
            qa1[m] = x2[bq1 + m * 2048];
            qb1[m] = x2[bq1 + m * 2048 + 32];
        }
    }

    v2f uqa0 = {0.f,0.f}, uqb0 = {0.f,0.f}, rsa0 = {0.f,0.f}, rsb0 = {0.f,0.f};
    v2f uqa1 = {0.f,0.f}, uqb1 = {0.f,0.f}, rsa1 = {0.f,0.f}, rsb1 = {0.f,0.f};
    #pragma unroll
    for (int m = 0; m < 8; m++) {
        uqa0 += qa0[m] * wqr[m];          // wq pre-scaled (incl. log2e)
        uqb0 += qb0[m] * wqr[m];
        rsa0 += qa0[m];
        rsb0 += qb0[m];
        uqa1 += qa1[m] * wqr[m];
        uqb1 += qb1[m] * wqr[m];
        rsa1 += qa1[m];
        rsb1 += qb1[m];
    }

    __syncthreads();     // the ONLY barrier: s_uk/s_uv ready

    // ---- stage 3: fused att + softmax + AV ----
    {
        v2f oa0 = {0.f, 0.f}, ob0 = {0.f, 0.f};
        v2f oa1 = {0.f, 0.f}, ob1 = {0.f, 0.f};
        float sum0 = 0.f, sum1 = 0.f;

        #pragma unroll
        for (int j = 0; j < 16; j++) {
            const float4 k4 = s_uk[t3][j][p3];    // 2-way bank alias: free
            const float4 v4 = s_uv[t3][j][p3];
            const v2f ka = {k4.x, k4.y}, kb = {k4.z, k4.w};
            const v2f va = {v4.x, v4.y}, vb = {v4.z, v4.w};

            v2f t0 = uqa0 * ka;
            t0 += uqb0 * kb;
            const float e0 = EXP_FN(t0.x + t0.y);
            sum0 += e0;
            oa0 += va * e0;
            ob0 += vb * e0;

            v2f t1 = uqa1 * ka;
            t1 += uqb1 * kb;
            const float e1 = EXP_FN(t1.x + t1.y);
            sum1 += e1;
            oa1 += va * e1;
            ob1 += vb * e1;
        }

        v2f* __restrict__ out2 = (v2f*)out;
        {
            const int i = ig * 2;
            const float rcp = RCP_FN(sum0);
            const v2f outa = oa0 * rcp + rsa0 * 0.125f;   // residual = mean/m
            const v2f outb = ob0 * rcp + rsb0 * 0.125f;
            const int obi = ((bb * 16 + i) * 64 + o) * 2048 + sp;
            out2[obi]      = outa;    // row y0
            out2[obi + 32] = outb;    // row y0+1
        }
        {
            const int i = ig * 2 + 1;
            const float rcp = RCP_FN(sum1);
            const v2f outa = oa1 * rcp + rsa1 * 0.125f;
            const v2f outb = ob1 * rcp + rsb1 * 0.125f;
            const int obi = ((bb * 16 + i) * 64 + o) * 2048 + sp;
            out2[obi]      = outa;
            out2[obi + 32] = outb;
        }
    }
}

extern "C" void kernel_launch(void* const* d_in, const int* in_sizes, int n_in,
                              void* d_out, int out_size, void* d_ws, size_t ws_size,
                              hipStream_t stream) {
    const float* x  = (const float*)d_in[0];
    const float* wq = (const float*)d_in[1];
    const float* wk = (const float*)d_in[2];
    const float* wv = (const float*)d_in[3];
    const float* wp = (const float*)d_in[4];
    float* out = (float*)d_out;
    // 4 bb * 64 o * 32 tile-pairs = 8192 blocks of 256 threads
    adapt_attn<<<dim3(8192), dim3(256), 0, stream>>>(x, wq, wk, wv, wp, out);
}

// Round 5
// 119.221 us; speedup vs baseline: 1.1857x; 1.1857x over previous
//
#include <hip/hip_runtime.h>

typedef float v2f __attribute__((ext_vector_type(2)));

// ---- problem ----
// x:[4,16,8,64,64] f32, w_q/w_k/w_v:[64,8] f32, w_p:[2] f32
// out:[4,16,64,64,64] f32
// Attention batch B = bb*64 + o: q-side channel i (all 16) row o;
// k/v-side channel o>>2, w_k/w_v rows (o&3)*16+j; uk += 2*pe; scale 0.125
// folded into w_q (plus log2e when exp2 available); residual = mean over m;
// single-pass softmax (|logit| << 88): out = (sum_j e_j*uv_j)/(sum_j e_j).
//
// R15 = R13 structure + forced packed-FP32 VALU. Evidence: dur*VALUBusy
// == ~26 us across R11/R13/R14 (three very different structures) and that
// matches a SCALAR v_fma_f32 count model -> hipcc is not emitting
// v_pk_fma_f32 for v2f arithmetic. Inline-asm pk_fma/pk_add/pk_mul on the
// three hot loops (q-conv, k/v conv, attention), with op_sel lo/hi
// broadcast so per-thread weights are consumed from their natural paired
// layout (no dup instructions, no extra VGPRs). Bit-identical math.
// Also: weight loads issued before the 32-load q burst.

#if __has_builtin(__builtin_amdgcn_exp2f)
  #define EXP_FN(x) __builtin_amdgcn_exp2f(x)
  #define QSCALE 0.18033688011112043f   // 0.125 * log2(e)
#else
  #define EXP_FN(x) __expf(x)
  #define QSCALE 0.125f
#endif
#if __has_builtin(__builtin_amdgcn_rcpf)
  #define RCP_FN(x) __builtin_amdgcn_rcpf(x)
#else
  #define RCP_FN(x) (1.0f/(x))
#endif

// acc += a * b   (two independent IEEE f32 FMAs, full rate on gfx90a+)
__device__ __forceinline__ void pk_fma(v2f& acc, v2f a, v2f b) {
    asm("v_pk_fma_f32 %0, %1, %2, %0" : "+v"(acc) : "v"(a), "v"(b));
}
// acc += a * b.x  (broadcast low word of pair b to both halves)
__device__ __forceinline__ void pk_fma_blo(v2f& acc, v2f a, v2f b) {
    asm("v_pk_fma_f32 %0, %1, %2, %0 op_sel:[0,0,0] op_sel_hi:[1,0,1]"
        : "+v"(acc) : "v"(a), "v"(b));
}
// acc += a * b.y  (broadcast high word of pair b to both halves)
__device__ __forceinline__ void pk_fma_bhi(v2f& acc, v2f a, v2f b) {
    asm("v_pk_fma_f32 %0, %1, %2, %0 op_sel:[0,1,0] op_sel_hi:[1,1,1]"
        : "+v"(acc) : "v"(a), "v"(b));
}
// acc += a
__device__ __forceinline__ void pk_add(v2f& acc, v2f a) {
    asm("v_pk_add_f32 %0, %1, %0" : "+v"(acc) : "v"(a));
}
// d = a * b
__device__ __forceinline__ v2f pk_mul(v2f a, v2f b) {
    v2f d;
    asm("v_pk_mul_f32 %0, %1, %2" : "=v"(d) : "v"(a), "v"(b));
    return d;
}

__global__ __launch_bounds__(256, 4) void adapt_attn(
    const float* __restrict__ x,  const float* __restrict__ wq,
    const float* __restrict__ wk, const float* __restrict__ wv,
    const float* __restrict__ wp, float* __restrict__ out)
{
    __shared__ __align__(16) v2f s_xk[2][8][2][16];   // 4 KB  [t][m][row][p]
    __shared__ float4 s_uk[2][16][16];                // 8 KB  [t][j][p]
    __shared__ float4 s_uv[2][16][16];                // 8 KB   -> 20480 total

    const int tid = threadIdx.x;          // 0..255
    const int bid = blockIdx.x;           // ((bb*64+o)*32)+tg ; 8192 blocks
    const int tg = bid & 31;
    const int o  = (bid >> 5) & 63;
    const int bb = bid >> 11;
    const int r = o & 3, qch = o >> 2;

    const v2f*    __restrict__ x2 = (const v2f*)x;    // v2f strides: m 2048, row 32
    const float4* __restrict__ x4 = (const float4*)x; // f4 strides: m 1024, row 16

    // ---- A: issue stage-1 k/v staging load (1 float4 per thread) ----
    float4 s1;
    {
        const int f = tid & 7, row = (tid >> 3) & 1, m = (tid >> 4) & 7, t = tid >> 7;
        const int tile = tg * 2 + t;
        const int y0 = (tile >> 1) << 1, w8 = (tile & 1) * 8;
        s1 = x4[((bb * 16 + qch) * 8 + m) * 1024 + (y0 + row) * 16 + w8 + f];
    }

    // ---- B: stage-2 weights from global (L1-resident, 2 KB), as 4 pairs ----
    const int p2 = tid & 15, j2 = (tid >> 4) & 15;   // per-thread j, both tiles
    v2f wk2[4], wv2[4];                               // [q] = {w[2q], w[2q+1]}
    {
        const float4* wk4 = (const float4*)wk;
        const float4* wv4 = (const float4*)wv;
        const int rb = (r * 16 + j2) * 2;
        *(float4*)&wk2[0] = wk4[rb];   *(float4*)&wk2[2] = wk4[rb + 1];
        *(float4*)&wv2[0] = wv4[rb];   *(float4*)&wv2[2] = wv4[rb + 1];
    }
    const float wp0 = wp[0], wp1 = wp[1];

    // ---- C: q loads + q-conv + residual (hides A/B latency) ----
    const int p3 = tid & 15, ig = (tid >> 4) & 7, t3 = tid >> 7;
    const int tile3 = tg * 2 + t3;
    const int y03 = (tile3 >> 1) << 1, ww03 = (tile3 & 1) << 4;
    const int sp = y03 * 32 + ww03 + p3;  // v2f offset within a 64x64 plane

    v2f wq2[4];                           // prescaled wq as pairs (same math as R13)
    #pragma unroll
    for (int q = 0; q < 4; q++) {
        wq2[q].x = QSCALE * wq[(o << 3) + 2 * q];     // uniform scalar loads
        wq2[q].y = QSCALE * wq[(o << 3) + 2 * q + 1];
    }

    v2f qa0[8], qb0[8], qa1[8], qb1[8];
    {
        const int bq0 = (bb * 16 + ig * 2) * 16384 + sp;
        const int bq1 = bq0 + 16384;
        #pragma unroll
        for (int m = 0; m < 8; m++) {                // lanes 0-15 coalesced 128B
            qa0[m] = x2[bq0 + m * 2048];
            qb0[m] = x2[bq0 + m * 2048 + 32];
            qa1[m] = x2[bq1 + m * 2048];
            qb1[m] = x2[bq1 + m * 2048 + 32];
        }
    }

    v2f uqa0 = {0.f,0.f}, uqb0 = {0.f,0.f}, rsa0 = {0.f,0.f}, rsb0 = {0.f,0.f};
    v2f uqa1 = {0.f,0.f}, uqb1 = {0.f,0.f}, rsa1 = {0.f,0.f}, rsb1 = {0.f,0.f};
    #pragma unroll
    for (int q = 0; q < 4; q++) {
        // m = 2q (low-word weight), m = 2q+1 (high-word weight)
        pk_fma_blo(uqa0, qa0[2*q],   wq2[q]);
        pk_fma_bhi(uqa0, qa0[2*q+1], wq2[q]);
        pk_fma_blo(uqb0, qb0[2*q],   wq2[q]);
        pk_fma_bhi(uqb0, qb0[2*q+1], wq2[q]);
        pk_fma_blo(uqa1, qa1[2*q],   wq2[q]);
        pk_fma_bhi(uqa1, qa1[2*q+1], wq2[q]);
        pk_fma_blo(uqb1, qb1[2*q],   wq2[q]);
        pk_fma_bhi(uqb1, qb1[2*q+1], wq2[q]);
        pk_add(rsa0, qa0[2*q]);  pk_add(rsa0, qa0[2*q+1]);
        pk_add(rsb0, qb0[2*q]);  pk_add(rsb0, qb0[2*q+1]);
        pk_add(rsa1, qa1[2*q]);  pk_add(rsa1, qa1[2*q+1]);
        pk_add(rsb1, qb1[2*q]);  pk_add(rsb1, qb1[2*q+1]);
    }

    // ---- D: LDS store for stage-1 tile ----
    {
        const int f = tid & 7, row = (tid >> 3) & 1, m = (tid >> 4) & 7, t = tid >> 7;
        *(float4*)&s_xk[t][m][row][f * 2] = s1;
    }
    __syncthreads();

    // ---- stage 2: build uk/uv[t][j2][p2] for both tiles (packed) ----
    const float step = 2.0f / 63.0f;
    #pragma unroll
    for (int t = 0; t < 2; t++) {
        const int tile = tg * 2 + t;
        const int y0 = (tile >> 1) << 1, ww0 = (tile & 1) << 4;
        const int wwp = ww0 + p2;
        const float lx0 = -1.0f + step * (float)(wwp << 1);
        const float lx1 = lx0 + step;
        const float ly0 = -1.0f + step * (float)y0;
        const float ly1 = ly0 + step;
        v2f ka = { 2.0f * (wp0 * lx0 + wp1 * ly0), 2.0f * (wp0 * lx1 + wp1 * ly0) };
        v2f kb = { 2.0f * (wp0 * lx0 + wp1 * ly1), 2.0f * (wp0 * lx1 + wp1 * ly1) };
        v2f va = {0.f, 0.f}, vb = {0.f, 0.f};

        #pragma unroll
        for (int q = 0; q < 4; q++) {
            const v2f xa0 = s_xk[t][2*q  ][0][p2];
            const v2f xb0 = s_xk[t][2*q  ][1][p2];
            const v2f xa1 = s_xk[t][2*q+1][0][p2];
            const v2f xb1 = s_xk[t][2*q+1][1][p2];
            pk_fma_blo(ka, xa0, wk2[q]);  pk_fma_bhi(ka, xa1, wk2[q]);
            pk_fma_blo(kb, xb0, wk2[q]);  pk_fma_bhi(kb, xb1, wk2[q]);
            pk_fma_blo(va, xa0, wv2[q]);  pk_fma_bhi(va, xa1, wv2[q]);
            pk_fma_blo(vb, xb0, wv2[q]);  pk_fma_bhi(vb, xb1, wv2[q]);
        }
        s_uk[t][j2][p2] = make_float4(ka.x, ka.y, kb.x, kb.y);
        s_uv[t][j2][p2] = make_float4(va.x, va.y, vb.x, vb.y);
    }
    __syncthreads();

    // ---- stage 3: fused att + softmax + AV (packed) ----
    {
        v2f oa0 = {0.f, 0.f}, ob0 = {0.f, 0.f};
        v2f oa1 = {0.f, 0.f}, ob1 = {0.f, 0.f};
        float sum0 = 0.f, sum1 = 0.f;

        #pragma unroll
        for (int j = 0; j < 16; j++) {
            const float4 k4 = s_uk[t3][j][p3];    // 4-dup broadcast: free
            const float4 v4 = s_uv[t3][j][p3];
            const v2f ka = {k4.x, k4.y}, kb = {k4.z, k4.w};
            const v2f va = {v4.x, v4.y}, vb = {v4.z, v4.w};

            v2f t0 = pk_mul(uqa0, ka);
            pk_fma(t0, uqb0, kb);
            const float e0 = EXP_FN(t0.x + t0.y);
            sum0 += e0;
            const v2f e20 = {e0, e0};
            pk_fma(oa0, va, e20);
            pk_fma(ob0, vb, e20);

            v2f t1 = pk_mul(uqa1, ka);
            pk_fma(t1, uqb1, kb);
            const float e1 = EXP_FN(t1.x + t1.y);
            sum1 += e1;
            const v2f e21 = {e1, e1};
            pk_fma(oa1, va, e21);
            pk_fma(ob1, vb, e21);
        }

        v2f* __restrict__ out2 = (v2f*)out;
        {
            const int i = ig * 2;
            const float rcp = RCP_FN(sum0);
            const v2f outa = oa0 * rcp + rsa0 * 0.125f;   // residual = mean/m
            const v2f outb = ob0 * rcp + rsb0 * 0.125f;
            const int obi = ((bb * 16 + i) * 64 + o) * 2048 + sp;
            out2[obi]      = outa;    // row y03
            out2[obi + 32] = outb;    // row y03+1
        }
        {
            const int i = ig * 2 + 1;
            const float rcp = RCP_FN(sum1);
            const v2f outa = oa1 * rcp + rsa1 * 0.125f;
            const v2f outb = ob1 * rcp + rsb1 * 0.125f;
            const int obi = ((bb * 16 + i) * 64 + o) * 2048 + sp;
            out2[obi]      = outa;
            out2[obi + 32] = outb;
        }
    }
}

extern "C" void kernel_launch(void* const* d_in, const int* in_sizes, int n_in,
                              void* d_out, int out_size, void* d_ws, size_t ws_size,
                              hipStream_t stream) {
    const float* x  = (const float*)d_in[0];
    const float* wq = (const float*)d_in[1];
    const float* wk = (const float*)d_in[2];
    const float* wv = (const float*)d_in[3];
    const float* wp = (const float*)d_in[4];
    float* out = (float*)d_out;
    // 4 bb * 64 o * 32 tile-pairs = 8192 blocks of 256 threads
    adapt_attn<<<dim3(8192), dim3(256), 0, stream>>>(x, wq, wk, wv, wp, out);
}